// Round 1
// baseline (843.626 us; speedup 1.0000x reference)
//
#include <hip/hip_runtime.h>
#include <math.h>

// GAT layer, restructured:
//   M  = W1n @ align_w  (16x64), Mt = W1t @ align_w (16x64)
//   Kt[h] = b1[h] + (W1n+W1t)@align_b
//   u_perm[b][m] = Kt[h(m)] + Mt[h(m)] @ x_target[b]        (kernel gat_u, 4 MB ws)
//   e[b,i] = leaky( sum_h w2[h]*relu( u[b,h] + M[h]@x_neigh[b,i] ) + b2 )
//   out[b] = elu( align_w @ (softmax(e) @ x_neigh[b]) + align_b )
// x_neigh (587 MB) is read exactly once; tile stays in registers (36 VGPR/lane).
// Cross-lane c-reduction for scores done on the VALU via DPP butterfly
// (xor1/xor2 quad_perm, xor7 row_half_mirror, xor15 row_mirror).

#define ALPHA 0.2f
static constexpr int Bn = 65536;
static constexpr int Nn = 35;
static constexpr int Cn = 64;

#define DPP_XOR1 0xB1   // quad_perm [1,0,3,2]
#define DPP_XOR2 0x4E   // quad_perm [2,3,0,1]
#define DPP_HMIR 0x141  // row_half_mirror = xor7
#define DPP_MIR  0x140  // row_mirror      = xor15

template<int CTRL>
__device__ __forceinline__ float dpp_mov(float x) {
  int r = __builtin_amdgcn_update_dpp(0, __builtin_bit_cast(int, x), CTRL, 0xF, 0xF, true);
  return __builtin_bit_cast(float, r);
}

// lane-local split bits for the butterfly; final h held by lane m:
__device__ __forceinline__ int h_of_m(int m) {
  int b0 = m & 1, b1 = (m >> 1) & 1, b2 = (m >> 2) & 1, b3 = (m >> 3) & 1;
  return (b0 ^ b2) | ((b1 ^ b2) << 1) | ((b0 ^ b3) << 2) | (b3 << 3);
}

// 16 partials p[h] per lane (lane = c-slice m) -> full sum over the 16-lane
// DPP row, scattered so lane m ends with value for h(m).
__device__ __forceinline__ float reduce_scatter16(const float p[16], int f1, int f2, int f3, int f4) {
  float q[8];
#pragma unroll
  for (int j = 0; j < 8; ++j) {
    float keep = f1 ? p[2*j+1] : p[2*j];
    float send = f1 ? p[2*j]   : p[2*j+1];
    q[j] = keep + dpp_mov<DPP_XOR1>(send);
  }
  float r[4];
#pragma unroll
  for (int j = 0; j < 4; ++j) {
    float keep = f2 ? q[2*j+1] : q[2*j];
    float send = f2 ? q[2*j]   : q[2*j+1];
    r[j] = keep + dpp_mov<DPP_XOR2>(send);
  }
  float s[2];
#pragma unroll
  for (int j = 0; j < 2; ++j) {
    float keep = f3 ? r[2*j+1] : r[2*j];
    float send = f3 ? r[2*j]   : r[2*j+1];
    s[j] = keep + dpp_mov<DPP_HMIR>(send);
  }
  float keep = f4 ? s[1] : s[0];
  float send = f4 ? s[0] : s[1];
  return keep + dpp_mov<DPP_MIR>(send);
}

__device__ __forceinline__ float row_allreduce_add(float x) {
  x += dpp_mov<DPP_XOR1>(x);
  x += dpp_mov<DPP_XOR2>(x);
  x += dpp_mov<DPP_HMIR>(x);
  x += dpp_mov<DPP_MIR>(x);
  return x;
}

// ---- kernel 1a: fold weights.  M[16][64], Mt[16][64], Kt[16] into ws ----
__global__ void gat_prep(const float* __restrict__ align_w, const float* __restrict__ align_b,
                         const float* __restrict__ a1w, const float* __restrict__ a1b,
                         float* __restrict__ wsM, float* __restrict__ wsMt, float* __restrict__ wsKt) {
  int t = blockIdx.x * 256 + threadIdx.x;
  if (t < 1024) {
    int h = t >> 6, c = t & 63;
    float accM = 0.f, accMt = 0.f;
    for (int d = 0; d < 64; ++d) {
      float w = align_w[d * 64 + c];
      accM  += a1w[h * 128 + 64 + d] * w;   // W1n part
      accMt += a1w[h * 128 + d] * w;        // W1t part
    }
    wsM[t] = accM;
    wsMt[t] = accMt;
  }
  if (t < 16) {
    float acc = a1b[t];
    for (int d = 0; d < 64; ++d)
      acc += (a1w[t * 128 + d] + a1w[t * 128 + 64 + d]) * align_b[d];
    wsKt[t] = acc;
  }
}

// ---- kernel 1b: u_perm[b*16+m] = Kt[h(m)] + Mt[h(m)] @ x_target[b] ----
__global__ void gat_u(const float* __restrict__ xt, const float* __restrict__ wsMt,
                      const float* __restrict__ wsKt, float* __restrict__ u_perm) {
  int gt = blockIdx.x * 256 + threadIdx.x;
  int b = gt >> 4, m = gt & 15;
  int hm = h_of_m(m);
  const float4* xr = (const float4*)(xt + (size_t)b * 64);
  const float4* Mr = (const float4*)(wsMt + hm * 64);
  float acc = wsKt[hm];
#pragma unroll
  for (int j = 0; j < 16; ++j) {
    float4 a = Mr[j], x = xr[j];
    acc += a.x * x.x + a.y * x.y + a.z * x.z + a.w * x.w;
  }
  u_perm[gt] = acc;
}

// ---- main fused kernel: one wave per b ----
template<bool PRECOMP_U>
__global__ __launch_bounds__(256, 2) void gat_main(
    const float* __restrict__ x_target, const float* __restrict__ x_neigh,
    const float* __restrict__ align_w, const float* __restrict__ align_b,
    const float* __restrict__ attn2_w, const float* __restrict__ attn2_b,
    const float* __restrict__ wsM, const float* __restrict__ wsMt,
    const float* __restrict__ wsKt, const float* __restrict__ u_perm,
    float* __restrict__ out, int waves_total) {
  __shared__ float W_lds[64 * 65];     // align_w, stride 65 -> conflict-free row reads
  __shared__ float xw_lds[4][64];      // per-wave xw broadcast buffer

  int tid = threadIdx.x;
  for (int idx = tid; idx < 4096; idx += 256) {
    int r = idx >> 6, c = idx & 63;
    W_lds[r * 65 + c] = align_w[idx];
  }
  __syncthreads();   // once, before the b-loop

  const int lane = tid & 63, wave = tid >> 6;
  const int m = lane & 15, g = lane >> 4;
  const int b0 = m & 1, b1 = (m >> 1) & 1, b2v = (m >> 2) & 1, b3 = (m >> 3) & 1;
  const int f1 = b0 ^ b2v, f2 = b1 ^ b2v, f3 = b0 ^ b3, f4 = b3;
  const int hm = f1 | (f2 << 1) | (f3 << 2) | (f4 << 3);

  // per-lane persistent constants
  float4 Ms[16];
#pragma unroll
  for (int h = 0; h < 16; ++h)
    Ms[h] = ((const float4*)(wsM + h * 64))[m];   // M[h][4m..4m+3]
  const float w2r = attn2_w[hm];
  const float b2r = attn2_b[0];
  const float biasr = align_b[lane];

  float4 Mts[16];
  float Ktr = 0.f;
  if (!PRECOMP_U) {
#pragma unroll
    for (int h = 0; h < 16; ++h)
      Mts[h] = ((const float4*)(wsMt + h * 64))[m];
    Ktr = wsKt[hm];
  }

  const int gw = blockIdx.x * 4 + wave;
  for (int b = gw; b < Bn; b += waves_total) {
    // ---- load x_neigh[b] tile into registers (coalesced float4) ----
    const float4* xb = (const float4*)(x_neigh + (size_t)b * Nn * Cn);
    float4 x[9];
#pragma unroll
    for (int k = 0; k < 9; ++k) {
      if (k < 8) {
        x[k] = xb[lane + 64 * k];
      } else {
        float4 z; z.x = z.y = z.z = z.w = 0.f;
        if (lane < 48) z = xb[lane + 512];
        x[8] = z;
      }
    }
    // lane holds rows i = g + 4k, cols [4m, 4m+4)

    // ---- per-b, per-h constant u[b][h(m)] ----
    float uval;
    if (PRECOMP_U) {
      uval = u_perm[(size_t)b * 16 + m];
    } else {
      float4 xt = ((const float4*)(x_target + (size_t)b * 64))[m];
      float up[16];
#pragma unroll
      for (int h = 0; h < 16; ++h)
        up[h] = Mts[h].x * xt.x + Mts[h].y * xt.y + Mts[h].z * xt.z + Mts[h].w * xt.w;
      uval = reduce_scatter16(up, f1, f2, f3, f4) + Ktr;
    }

    // ---- attention scores e[i = g+4k] ----
    float ex[9];
    float mloc = -1e30f;
#pragma unroll
    for (int k = 0; k < 9; ++k) {
      float p[16];
#pragma unroll
      for (int h = 0; h < 16; ++h)
        p[h] = Ms[h].x * x[k].x + Ms[h].y * x[k].y + Ms[h].z * x[k].z + Ms[h].w * x[k].w;
      float P = reduce_scatter16(p, f1, f2, f3, f4);      // pre-act for h(m), full c-sum
      float rr = fmaxf(P + uval, 0.f) * w2r;              // relu * w2[h]
      float esum = row_allreduce_add(rr) + b2r;           // sum over 16 h
      float e = fmaxf(esum, 0.f) + ALPHA * fminf(esum, 0.f);  // leaky_relu
      if (k == 8 && g == 3) e = -1e30f;                   // i=35 doesn't exist
      ex[k] = e;
      mloc = fmaxf(mloc, e);
    }

    // ---- softmax over all 35 (cross-row reduce) ----
    mloc = fmaxf(mloc, __shfl_xor(mloc, 16));
    mloc = fmaxf(mloc, __shfl_xor(mloc, 32));
    float sloc = 0.f;
#pragma unroll
    for (int k = 0; k < 9; ++k) {
      ex[k] = __expf(ex[k] - mloc);
      sloc += ex[k];
    }
    sloc += __shfl_xor(sloc, 16);
    sloc += __shfl_xor(sloc, 32);
    const float rS = 1.f / sloc;

    // ---- weighted neighbor sum, xw[4m..4m+3] ----
    float4 xw; xw.x = xw.y = xw.z = xw.w = 0.f;
#pragma unroll
    for (int k = 0; k < 9; ++k) {
      xw.x = fmaf(ex[k], x[k].x, xw.x);
      xw.y = fmaf(ex[k], x[k].y, xw.y);
      xw.z = fmaf(ex[k], x[k].z, xw.z);
      xw.w = fmaf(ex[k], x[k].w, xw.w);
    }
    xw.x += __shfl_xor(xw.x, 16); xw.x += __shfl_xor(xw.x, 32);
    xw.y += __shfl_xor(xw.y, 16); xw.y += __shfl_xor(xw.y, 32);
    xw.z += __shfl_xor(xw.z, 16); xw.z += __shfl_xor(xw.z, 32);
    xw.w += __shfl_xor(xw.w, 16); xw.w += __shfl_xor(xw.w, 32);
    xw.x *= rS; xw.y *= rS; xw.z *= rS; xw.w *= rS;

    // ---- broadcast xw through LDS, final 64x64 matvec, elu ----
    if (g == 0)
      *(float4*)(&xw_lds[wave][4 * m]) = xw;
    asm volatile("s_waitcnt lgkmcnt(0)" ::: "memory");

    float hp = biasr;
#pragma unroll
    for (int t = 0; t < 16; ++t) {
      float4 xv = *(const float4*)(&xw_lds[wave][4 * t]);
      hp = fmaf(W_lds[lane * 65 + 4 * t + 0], xv.x, hp);
      hp = fmaf(W_lds[lane * 65 + 4 * t + 1], xv.y, hp);
      hp = fmaf(W_lds[lane * 65 + 4 * t + 2], xv.z, hp);
      hp = fmaf(W_lds[lane * 65 + 4 * t + 3], xv.w, hp);
    }
    float en = __expf(fminf(hp, 0.f)) - 1.f;   // elu negative branch
    out[(size_t)b * 64 + lane] = hp > 0.f ? hp : en;
  }
}

extern "C" void kernel_launch(void* const* d_in, const int* in_sizes, int n_in,
                              void* d_out, int out_size, void* d_ws, size_t ws_size,
                              hipStream_t stream) {
  const float* x_target = (const float*)d_in[0];
  const float* x_neigh  = (const float*)d_in[1];
  const float* align_w  = (const float*)d_in[2];
  const float* align_b  = (const float*)d_in[3];
  // d_in[4] = attn1_w, d_in[5] = attn1_b (consumed only by gat_prep)
  const float* attn1_w  = (const float*)d_in[4];
  const float* attn1_b  = (const float*)d_in[5];
  const float* attn2_w  = (const float*)d_in[6];
  const float* attn2_b  = (const float*)d_in[7];
  float* out = (float*)d_out;

  float* ws = (float*)d_ws;
  float* wsM  = ws;            // 1024 floats
  float* wsMt = ws + 1024;     // 1024 floats
  float* wsKt = ws + 2048;     // 16 floats
  float* u_perm = ws + 2064;   // B*16 floats (4 MB)
  size_t need = (2064 + (size_t)Bn * 16) * sizeof(float);
  bool precomp = ws_size >= need;

  gat_prep<<<4, 256, 0, stream>>>(align_w, align_b, attn1_w, attn1_b, wsM, wsMt, wsKt);

  const int blocks = 1024;
  const int waves_total = blocks * 4;
  if (precomp) {
    gat_u<<<(Bn * 16) / 256, 256, 0, stream>>>(x_target, wsMt, wsKt, u_perm);
    gat_main<true><<<blocks, 256, 0, stream>>>(x_target, x_neigh, align_w, align_b,
                                               attn2_w, attn2_b, wsM, wsMt, wsKt,
                                               u_perm, out, waves_total);
  } else {
    gat_main<false><<<blocks, 256, 0, stream>>>(x_target, x_neigh, align_w, align_b,
                                                attn2_w, attn2_b, wsM, wsMt, wsKt,
                                                u_perm, out, waves_total);
  }
}

// Round 2
// 821.838 us; speedup vs baseline: 1.0265x; 1.0265x over previous
//
#include <hip/hip_runtime.h>
#include <math.h>

// GAT layer, restructured (fp32 throughout):
//   M  = W1n @ align_w (16x64), Mt = W1t @ align_w (16x64), Kt = b1 + (W1n+W1t)@align_b
//   u[b][h] = Kt[h] + Mt[h] @ x_target[b]                 (kernel gat_u, 4 MB ws)
//   e[b,i] = leaky( sum_h w2[h]*relu( u[b,h] + M[h]@x_neigh[b,i] ) + b2 )
//   out[b] = elu( align_w @ (softmax(e) @ x_neigh[b]) + align_b )
// x_neigh (587 MB) read exactly once; per-b tile lives in registers.
// R2: selection-free DPP reduce-scatter (per-lane pre-permuted order, lane m
// ends with h=m), v_pk_*_f32 packed math, launch_bounds(256,3) for 3 waves/SIMD.

#define ALPHA 0.2f
static constexpr int Bn = 65536;
static constexpr int Nn = 35;
static constexpr int Cn = 64;

typedef float v2f __attribute__((ext_vector_type(2)));
typedef float v4f __attribute__((ext_vector_type(4)));

#define DPP_XOR1 0xB1   // quad_perm [1,0,3,2]
#define DPP_XOR2 0x4E   // quad_perm [2,3,0,1]
#define DPP_HMIR 0x141  // row_half_mirror = xor7
#define DPP_MIR  0x140  // row_mirror      = xor15

template<int CTRL>
__device__ __forceinline__ float dpp_mov(float x) {
  int r = __builtin_amdgcn_update_dpp(0, __builtin_bit_cast(int, x), CTRL, 0xF, 0xF, true);
  return __builtin_bit_cast(float, r);
}

__device__ __forceinline__ v2f pk_mul(v2f a, v2f b) {
  v2f d; asm("v_pk_mul_f32 %0, %1, %2" : "=v"(d) : "v"(a), "v"(b)); return d;
}
__device__ __forceinline__ v2f pk_fma(v2f a, v2f b, v2f c) {
  v2f d; asm("v_pk_fma_f32 %0, %1, %2, %3" : "=v"(d) : "v"(a), "v"(b), "v"(c)); return d;
}

// Storage-order permutation making the butterfly selection-free.
// Stage decision functionals: g1=l0^l2, g2=l1^l2, g3=l2^l3, g4=l3; each
// stage's future bits are invariant under earlier DPP masks (1,2,7,15).
// Lane m stores, at position pos, the partial for h = perm_h(pos, m);
// after the 4 stages lane m holds the full 16-lane sum for h = m.
__device__ __forceinline__ int perm_h(int pos, int m) {
  int p3 = (pos >> 3) & 1;
  int e  = ((pos >> 2) ^ (pos >> 3)) & 1;
  return (pos ^ m) ^ (e ? 3 : 0) ^ (p3 ? 4 : 0);
}

// selection-free sum reduce-scatter over each 16-lane DPP row
__device__ __forceinline__ float reduce_scatter16(const float p[16]) {
  float q[8];
#pragma unroll
  for (int j = 0; j < 8; ++j) q[j] = p[2*j] + dpp_mov<DPP_XOR1>(p[2*j+1]);
  float r[4];
#pragma unroll
  for (int j = 0; j < 4; ++j) r[j] = q[2*j] + dpp_mov<DPP_XOR2>(q[2*j+1]);
  float s[2];
#pragma unroll
  for (int j = 0; j < 2; ++j) s[j] = r[2*j] + dpp_mov<DPP_HMIR>(r[2*j+1]);
  return s[0] + dpp_mov<DPP_MIR>(s[1]);
}

__device__ __forceinline__ float row_allreduce_add(float x) {
  x += dpp_mov<DPP_XOR1>(x);
  x += dpp_mov<DPP_XOR2>(x);
  x += dpp_mov<DPP_HMIR>(x);
  x += dpp_mov<DPP_MIR>(x);
  return x;
}

// ---- kernel 1a: fold weights.  M[16][64], Mt[16][64], Kt[16] into ws ----
__global__ void gat_prep(const float* __restrict__ align_w, const float* __restrict__ align_b,
                         const float* __restrict__ a1w, const float* __restrict__ a1b,
                         float* __restrict__ wsM, float* __restrict__ wsMt, float* __restrict__ wsKt) {
  int t = blockIdx.x * 256 + threadIdx.x;
  if (t < 1024) {
    int h = t >> 6, c = t & 63;
    float accM = 0.f, accMt = 0.f;
    for (int d = 0; d < 64; ++d) {
      float w = align_w[d * 64 + c];
      accM  += a1w[h * 128 + 64 + d] * w;   // W1n part
      accMt += a1w[h * 128 + d] * w;        // W1t part
    }
    wsM[t] = accM;
    wsMt[t] = accMt;
  }
  if (t < 16) {
    float acc = a1b[t];
    for (int d = 0; d < 64; ++d)
      acc += (a1w[t * 128 + d] + a1w[t * 128 + 64 + d]) * align_b[d];
    wsKt[t] = acc;
  }
}

// ---- kernel 1b: u[b*16+h] = Kt[h] + Mt[h] @ x_target[b]  (h = gt&15) ----
__global__ void gat_u(const float* __restrict__ xt, const float* __restrict__ wsMt,
                      const float* __restrict__ wsKt, float* __restrict__ u_arr) {
  int gt = blockIdx.x * 256 + threadIdx.x;
  int b = gt >> 4, h = gt & 15;
  const v4f* xr = (const v4f*)(xt + (size_t)b * 64);
  const v4f* Mr = (const v4f*)(wsMt + h * 64);
  float acc = wsKt[h];
#pragma unroll
  for (int j = 0; j < 16; ++j) {
    v4f a = Mr[j], x = xr[j];
    acc += a.x * x.x + a.y * x.y + a.z * x.z + a.w * x.w;
  }
  u_arr[gt] = acc;
}

// ---- main fused kernel: one wave per b ----
template<bool PRECOMP_U, int MINWAVES>
__global__ __launch_bounds__(256, MINWAVES) void gat_main(
    const float* __restrict__ x_target, const float* __restrict__ x_neigh,
    const float* __restrict__ align_w, const float* __restrict__ align_b,
    const float* __restrict__ attn2_w, const float* __restrict__ attn2_b,
    const float* __restrict__ wsM, const float* __restrict__ wsMt,
    const float* __restrict__ wsKt, const float* __restrict__ u_arr,
    float* __restrict__ out, int waves_total) {
  __shared__ float W_lds[64 * 65];     // align_w, stride 65 -> conflict-free row reads
  __shared__ float xw_lds[4][64];      // per-wave xw broadcast buffer

  int tid = threadIdx.x;
  for (int idx = tid; idx < 4096; idx += 256) {
    int r = idx >> 6, c = idx & 63;
    W_lds[r * 65 + c] = align_w[idx];
  }
  __syncthreads();   // once, before the b-loop

  const int lane = tid & 63, wave = tid >> 6;
  const int m = lane & 15, g = lane >> 4;

  // per-lane persistent constants, permuted storage order (pos-indexed)
  v2f Mlo[16], Mhi[16];
#pragma unroll
  for (int pos = 0; pos < 16; ++pos) {
    int h = perm_h(pos, m);
    v4f Mv = ((const v4f*)(wsM + h * 64))[m];   // M[h][4m..4m+3]
    Mlo[pos] = __builtin_shufflevector(Mv, Mv, 0, 1);
    Mhi[pos] = __builtin_shufflevector(Mv, Mv, 2, 3);
  }
  const float w2r = attn2_w[m];           // lane m ends with h = m
  const float b2r = attn2_b[0];
  const float biasr = align_b[lane];
  const int wrow = lane * 65;

  v2f Mtlo[16], Mthi[16];
  float Ktr = 0.f;
  if (!PRECOMP_U) {
#pragma unroll
    for (int pos = 0; pos < 16; ++pos) {
      int h = perm_h(pos, m);
      v4f Mv = ((const v4f*)(wsMt + h * 64))[m];
      Mtlo[pos] = __builtin_shufflevector(Mv, Mv, 0, 1);
      Mthi[pos] = __builtin_shufflevector(Mv, Mv, 2, 3);
    }
    Ktr = wsKt[m];
  }

  const int gw = blockIdx.x * 4 + wave;
  for (int b = gw; b < Bn; b += waves_total) {
    // ---- load x_neigh[b] tile into registers (coalesced dwordx4) ----
    const v4f* xb = (const v4f*)(x_neigh + (size_t)b * Nn * Cn);
    v4f x[9];
#pragma unroll
    for (int k = 0; k < 8; ++k) x[k] = xb[lane + 64 * k];
    {
      v4f z = {0.f, 0.f, 0.f, 0.f};
      if (lane < 48) z = xb[512 + lane];
      x[8] = z;
    }
    // lane holds rows i = g + 4k, cols [4m, 4m+4)

    // ---- per-b, per-h constant u[b][m] ----
    float uval;
    if (PRECOMP_U) {
      uval = u_arr[(size_t)b * 16 + m];
    } else {
      v4f xt4 = ((const v4f*)(x_target + (size_t)b * 64))[m];
      v2f xtlo = __builtin_shufflevector(xt4, xt4, 0, 1);
      v2f xthi = __builtin_shufflevector(xt4, xt4, 2, 3);
      float up[16];
#pragma unroll
      for (int pos = 0; pos < 16; ++pos) {
        v2f t = pk_mul(Mtlo[pos], xtlo);
        t = pk_fma(Mthi[pos], xthi, t);
        up[pos] = t.x + t.y;
      }
      uval = reduce_scatter16(up) + Ktr;
    }

    // ---- attention scores e[i = g+4k] ----
    float ex[9];
    float mloc = -1e30f;
#pragma unroll
    for (int k = 0; k < 9; ++k) {
      v2f xlo = __builtin_shufflevector(x[k], x[k], 0, 1);
      v2f xhi = __builtin_shufflevector(x[k], x[k], 2, 3);
      float p[16];
#pragma unroll
      for (int pos = 0; pos < 16; ++pos) {
        v2f t = pk_mul(Mlo[pos], xlo);
        t = pk_fma(Mhi[pos], xhi, t);
        p[pos] = t.x + t.y;
      }
      float P = reduce_scatter16(p);                      // full c-sum for h=m
      float rr = fmaxf(P + uval, 0.f) * w2r;              // relu * w2[h]
      float esum = row_allreduce_add(rr) + b2r;           // sum over 16 h
      float e = fmaxf(esum, 0.f) + ALPHA * fminf(esum, 0.f);  // leaky_relu
      if (k == 8 && g == 3) e = -1e30f;                   // i=35 doesn't exist
      ex[k] = e;
      mloc = fmaxf(mloc, e);
    }

    // ---- softmax over all 35 (cross-row reduce) ----
    mloc = fmaxf(mloc, __shfl_xor(mloc, 16));
    mloc = fmaxf(mloc, __shfl_xor(mloc, 32));
    float sloc = 0.f;
#pragma unroll
    for (int k = 0; k < 9; ++k) {
      ex[k] = __expf(ex[k] - mloc);
      sloc += ex[k];
    }
    sloc += __shfl_xor(sloc, 16);
    sloc += __shfl_xor(sloc, 32);
    const float rS = 1.f / sloc;

    // ---- weighted neighbor sum, xw[4m..4m+3] ----
    v4f xw = {0.f, 0.f, 0.f, 0.f};
#pragma unroll
    for (int k = 0; k < 9; ++k) {
      xw.x = fmaf(ex[k], x[k].x, xw.x);
      xw.y = fmaf(ex[k], x[k].y, xw.y);
      xw.z = fmaf(ex[k], x[k].z, xw.z);
      xw.w = fmaf(ex[k], x[k].w, xw.w);
    }
    xw.x += __shfl_xor(xw.x, 16); xw.x += __shfl_xor(xw.x, 32);
    xw.y += __shfl_xor(xw.y, 16); xw.y += __shfl_xor(xw.y, 32);
    xw.z += __shfl_xor(xw.z, 16); xw.z += __shfl_xor(xw.z, 32);
    xw.w += __shfl_xor(xw.w, 16); xw.w += __shfl_xor(xw.w, 32);
    xw *= rS;

    // ---- broadcast xw through LDS, final 64x64 matvec (packed), elu ----
    if (g == 0)
      *(v4f*)(&xw_lds[wave][4 * m]) = xw;
    asm volatile("s_waitcnt lgkmcnt(0)" ::: "memory");

    v2f hp2 = {0.f, 0.f};
#pragma unroll
    for (int t = 0; t < 16; ++t) {
      v2f xv0 = *(const v2f*)(&xw_lds[wave][4 * t]);
      v2f xv1 = *(const v2f*)(&xw_lds[wave][4 * t + 2]);
      int a = wrow + 4 * t;
      v2f w0 = { W_lds[a],     W_lds[a + 1] };
      v2f w1 = { W_lds[a + 2], W_lds[a + 3] };
      hp2 = pk_fma(w0, xv0, hp2);
      hp2 = pk_fma(w1, xv1, hp2);
    }
    float hp = biasr + hp2.x + hp2.y;
    float en = __expf(fminf(hp, 0.f)) - 1.f;   // elu negative branch
    out[(size_t)b * 64 + lane] = hp > 0.f ? hp : en;
  }
}

extern "C" void kernel_launch(void* const* d_in, const int* in_sizes, int n_in,
                              void* d_out, int out_size, void* d_ws, size_t ws_size,
                              hipStream_t stream) {
  const float* x_target = (const float*)d_in[0];
  const float* x_neigh  = (const float*)d_in[1];
  const float* align_w  = (const float*)d_in[2];
  const float* align_b  = (const float*)d_in[3];
  const float* attn1_w  = (const float*)d_in[4];
  const float* attn1_b  = (const float*)d_in[5];
  const float* attn2_w  = (const float*)d_in[6];
  const float* attn2_b  = (const float*)d_in[7];
  float* out = (float*)d_out;

  float* ws = (float*)d_ws;
  float* wsM  = ws;            // 1024 floats
  float* wsMt = ws + 1024;     // 1024 floats
  float* wsKt = ws + 2048;     // 16 floats
  float* u_arr = ws + 2064;    // B*16 floats (4 MB)
  size_t need = (2064 + (size_t)Bn * 16) * sizeof(float);
  bool precomp = ws_size >= need;

  gat_prep<<<4, 256, 0, stream>>>(align_w, align_b, attn1_w, attn1_b, wsM, wsMt, wsKt);

  const int blocks = 2048;
  const int waves_total = blocks * 4;
  if (precomp) {
    gat_u<<<(Bn * 16) / 256, 256, 0, stream>>>(x_target, wsMt, wsKt, u_arr);
    gat_main<true, 3><<<blocks, 256, 0, stream>>>(x_target, x_neigh, align_w, align_b,
                                                  attn2_w, attn2_b, wsM, wsMt, wsKt,
                                                  u_arr, out, waves_total);
  } else {
    gat_main<false, 2><<<blocks, 256, 0, stream>>>(x_target, x_neigh, align_w, align_b,
                                                   attn2_w, attn2_b, wsM, wsMt, wsKt,
                                                   u_arr, out, waves_total);
  }
}